// Round 7
// baseline (303.558 us; speedup 1.0000x reference)
//
#include <hip/hip_runtime.h>

typedef __attribute__((ext_vector_type(8))) short bf16x8;
typedef __attribute__((ext_vector_type(4))) float f32x4;
typedef __attribute__((ext_vector_type(2))) unsigned u32x2;

#define M0F 14.0f

__device__ inline float bf2f(unsigned short b) {
    unsigned u = ((unsigned)b) << 16;
    float f; __builtin_memcpy(&f, &u, 4); return f;
}
__device__ inline unsigned short f2bf(float f) {
    unsigned u; __builtin_memcpy(&u, &f, 4);
    u = (u + 0x7fff + ((u >> 16) & 1)) >> 16;
    return (unsigned short)u;
}
__device__ inline unsigned pack2(float a, float b) {
    return (unsigned)f2bf(a) | ((unsigned)f2bf(b) << 16);
}

// LDS-visibility barrier; leaves global stores in flight
#define LDS_BARRIER() do { \
    asm volatile("s_waitcnt lgkmcnt(0)" ::: "memory"); \
    __builtin_amdgcn_s_barrier(); \
} while (0)

// ---------------- W [K][N] f32 -> Wt [N][K=512] bf16 ----------------
__global__ __launch_bounds__(256) void transpose_w(
    const float* __restrict__ W, unsigned short* __restrict__ Wt, int ldn)
{
    __shared__ unsigned short t[64][72];
    const int n0 = blockIdx.x * 64, k0 = blockIdx.y * 64;
    const int tid = threadIdx.x;
    for (int i = tid; i < 1024; i += 256) {
        int r = i >> 4, c4 = (i & 15) << 2;
        float4 v = *(const float4*)(W + (size_t)(k0 + r) * ldn + n0 + c4);
        t[c4 + 0][r] = f2bf(v.x); t[c4 + 1][r] = f2bf(v.y);
        t[c4 + 2][r] = f2bf(v.z); t[c4 + 3][r] = f2bf(v.w);
    }
    __syncthreads();
    for (int i = tid; i < 512; i += 256) {
        int n = i >> 3, k4 = (i & 7) << 3;
        bf16x8 v = *(const bf16x8*)&t[n][k4];
        *(bf16x8*)(Wt + (size_t)(n0 + n) * 512 + k0 + k4) = v;
    }
}

// ---------------- qkv = x @ Wqkv via bf16 MFMA ----------------
__global__ __launch_bounds__(256) void qkv_mfma(
    const float* __restrict__ x, const unsigned short* __restrict__ Wt,
    unsigned short* __restrict__ qkvb)
{
    __shared__ unsigned short Asm[64 * 64];
    __shared__ unsigned short Bsm[64 * 64];
    const int n0 = blockIdx.x * 64, m0 = blockIdx.y * 64;
    const int tid = threadIdx.x;
    const int w = tid >> 6, lane = tid & 63;
    const int cl = lane & 15, rg = lane >> 4;
    const int r0s = tid >> 3, c0s = (tid & 7) << 3;
    const int r1s = (tid + 256) >> 3;
    const int l0 = r0s * 64 + (c0s ^ ((r0s & 7) << 3));
    const int l1 = r1s * 64 + (c0s ^ ((r1s & 7) << 3));

    f32x4 acc[4];
    #pragma unroll
    for (int nt = 0; nt < 4; ++nt) acc[nt] = (f32x4){0.f, 0.f, 0.f, 0.f};

    for (int k0 = 0; k0 < 512; k0 += 64) {
        __syncthreads();
        {
            const float* ap = x + (size_t)(m0 + r0s) * 512 + k0 + c0s;
            float4 f0 = *(const float4*)ap, f1 = *(const float4*)(ap + 4);
            bf16x8 av; unsigned short* pp = (unsigned short*)&av;
            pp[0] = f2bf(f0.x); pp[1] = f2bf(f0.y); pp[2] = f2bf(f0.z); pp[3] = f2bf(f0.w);
            pp[4] = f2bf(f1.x); pp[5] = f2bf(f1.y); pp[6] = f2bf(f1.z); pp[7] = f2bf(f1.w);
            *(bf16x8*)&Asm[l0] = av;
            const float* aq = x + (size_t)(m0 + r1s) * 512 + k0 + c0s;
            float4 g0 = *(const float4*)aq, g1 = *(const float4*)(aq + 4);
            bf16x8 aw; unsigned short* qq = (unsigned short*)&aw;
            qq[0] = f2bf(g0.x); qq[1] = f2bf(g0.y); qq[2] = f2bf(g0.z); qq[3] = f2bf(g0.w);
            qq[4] = f2bf(g1.x); qq[5] = f2bf(g1.y); qq[6] = f2bf(g1.z); qq[7] = f2bf(g1.w);
            *(bf16x8*)&Asm[l1] = aw;
        }
        *(bf16x8*)&Bsm[l0] = *(const bf16x8*)(Wt + (size_t)(n0 + r0s) * 512 + k0 + c0s);
        *(bf16x8*)&Bsm[l1] = *(const bf16x8*)(Wt + (size_t)(n0 + r1s) * 512 + k0 + c0s);
        __syncthreads();

        bf16x8 af[2];
        af[0] = *(const bf16x8*)&Asm[(w * 16 + cl) * 64 + ((rg * 8) ^ ((cl & 7) << 3))];
        af[1] = *(const bf16x8*)&Asm[(w * 16 + cl) * 64 + ((32 + rg * 8) ^ ((cl & 7) << 3))];
        #pragma unroll
        for (int nt = 0; nt < 4; ++nt) {
            #pragma unroll
            for (int ks = 0; ks < 2; ++ks) {
                bf16x8 bfr = *(const bf16x8*)&Bsm[(nt * 16 + cl) * 64 + ((ks * 32 + rg * 8) ^ ((cl & 7) << 3))];
                acc[nt] = __builtin_amdgcn_mfma_f32_16x16x32_bf16(af[ks], bfr, acc[nt], 0, 0, 0);
            }
        }
    }
    #pragma unroll
    for (int nt = 0; nt < 4; ++nt)
        #pragma unroll
        for (int r = 0; r < 4; ++r)
            qkvb[(size_t)(m0 + w * 16 + rg * 4 + r) * 1536 + n0 + nt * 16 + cl] = f2bf(acc[nt][r]);
}

// ---------------- V transpose: qkv V columns -> vT[h][d][key] ----------------
__global__ __launch_bounds__(256) void transpose_v(
    const unsigned short* __restrict__ qkvb, unsigned short* __restrict__ vT)
{
    __shared__ unsigned short tile[64][72];
    const int h = blockIdx.y, k0 = blockIdx.x * 64;
    const int tid = threadIdx.x;

    for (int c = tid; c < 512; c += 256) {
        int key = c >> 3, d0 = (c & 7) << 3;
        bf16x8 v = *(const bf16x8*)(qkvb + (size_t)(k0 + key) * 1536 + 1024 + h * 64 + d0);
        #pragma unroll
        for (int j = 0; j < 8; ++j) tile[d0 + j][key] = ((const unsigned short*)&v)[j];
    }
    __syncthreads();
    for (int c = tid; c < 512; c += 256) {
        int d = c >> 3, kk0 = (c & 7) << 3;
        bf16x8 v = *(const bf16x8*)&tile[d][kk0];
        *(bf16x8*)(vT + ((size_t)h * 64 + d) * 4096 + k0 + kk0) = v;
    }
}

// ---------------- pass 1: partial row sums, K-split x4, LDS-staged ----------------
// grid 2048: h = bid&7 (XCD pin), s = (bid>>3)&3 (key quarter), rb = bid>>5 (64 rows)
__global__ __launch_bounds__(256) void attn_lsum(
    const unsigned short* __restrict__ qkvb, float* __restrict__ lsum_part)
{
    __shared__ unsigned short Ksm[2][64 * 64];
    const int bid = blockIdx.x;
    const int h = bid & 7, s = (bid >> 3) & 3, rb = bid >> 5;
    const int tid = threadIdx.x;
    const int w = tid >> 6, lane = tid & 63;
    const int cl = lane & 15, rg = lane >> 4;
    const int r0 = rb * 64 + w * 16;
    const int kb = s * 1024;

    bf16x8 qf[2];
    #pragma unroll
    for (int ks = 0; ks < 2; ++ks) {
        qf[ks] = *(const bf16x8*)(qkvb + (size_t)(r0 + cl) * 1536 + h * 64 + ks * 32 + rg * 8);
        unsigned short* qp = (unsigned short*)&qf[ks];
        #pragma unroll
        for (int j = 0; j < 8; ++j) qp[j] = f2bf(bf2f(qp[j]) * 0.125f);
    }

    const unsigned short* Kg = qkvb + 512 + h * 64;

    const int kr0 = tid >> 3,          kc0 = (tid & 7) << 3;
    const int kr1 = (tid + 256) >> 3;
    const int ld0 = kr0 * 64 + (kc0 ^ ((kr0 & 7) << 3));
    const int ld1 = kr1 * 64 + (kc0 ^ ((kr1 & 7) << 3));

    {
        bf16x8 ka = *(const bf16x8*)(Kg + (size_t)(kb + kr0) * 1536 + kc0);
        bf16x8 kbv = *(const bf16x8*)(Kg + (size_t)(kb + kr1) * 1536 + kc0);
        *(bf16x8*)&Ksm[0][ld0] = ka;
        *(bf16x8*)&Ksm[0][ld1] = kbv;
    }
    float lsum = 0.f;
    for (int t = 0; t < 16; ++t) {
        LDS_BARRIER();
        const int cur = t & 1;
        bf16x8 ka, kbv;
        if (t < 15) {
            const int k0n = kb + (t + 1) * 64;
            ka  = *(const bf16x8*)(Kg + (size_t)(k0n + kr0) * 1536 + kc0);
            kbv = *(const bf16x8*)(Kg + (size_t)(k0n + kr1) * 1536 + kc0);
        }
        #pragma unroll
        for (int nt = 0; nt < 4; ++nt) {
            const int key = nt * 16 + cl;
            f32x4 acc = {0.f, 0.f, 0.f, 0.f};
            #pragma unroll
            for (int ks = 0; ks < 2; ++ks) {
                bf16x8 kf = *(const bf16x8*)&Ksm[cur][key * 64 + ((ks * 32 + rg * 8) ^ ((key & 7) << 3))];
                acc = __builtin_amdgcn_mfma_f32_16x16x32_bf16(kf, qf[ks], acc, 0, 0, 0);
            }
            #pragma unroll
            for (int r = 0; r < 4; ++r) lsum += __expf(acc[r] - M0F);
        }
        if (t < 15) {
            *(bf16x8*)&Ksm[cur ^ 1][ld0] = ka;
            *(bf16x8*)&Ksm[cur ^ 1][ld1] = kbv;
        }
    }
    lsum += __shfl_xor(lsum, 16);
    lsum += __shfl_xor(lsum, 32);
    if (rg == 0)
        lsum_part[((size_t)(s * 8 + h) << 12) + r0 + cl] = lsum;
}

// ---------------- pass 2: P write + partial PV; K staged, V direct from L2 ----------------
// grid 1024: h = bid&7, s2 = (bid>>3)&1, rb = bid>>4; 24KB LDS -> 6 blocks/CU
__global__ __launch_bounds__(256, 6) void attn_pass2(
    const unsigned short* __restrict__ qkvb,
    const unsigned short* __restrict__ vT,
    const float* __restrict__ lsum_part,
    float* __restrict__ attn,
    float* __restrict__ opart)
{
    __shared__ unsigned short Ksm[2][64 * 64];
    __shared__ unsigned short Psm[4 * 16 * 64];

    const int bid = blockIdx.x;
    const int h = bid & 7, s2 = (bid >> 3) & 1, rb = bid >> 4;
    const int tid = threadIdx.x;
    const int w = tid >> 6, lane = tid & 63;
    const int cl = lane & 15, rg = lane >> 4;
    const int r0 = rb * 64 + w * 16;
    const int kb = s2 * 2048;

    bf16x8 qf[2];
    #pragma unroll
    for (int ks = 0; ks < 2; ++ks) {
        qf[ks] = *(const bf16x8*)(qkvb + (size_t)(r0 + cl) * 1536 + h * 64 + ks * 32 + rg * 8);
        unsigned short* qp = (unsigned short*)&qf[ks];
        #pragma unroll
        for (int j = 0; j < 8; ++j) qp[j] = f2bf(bf2f(qp[j]) * 0.125f);
    }

    const int row = r0 + cl;
    const float invl = 1.f / (lsum_part[(size_t)(0 * 8 + h) * 4096 + row] +
                              lsum_part[(size_t)(1 * 8 + h) * 4096 + row] +
                              lsum_part[(size_t)(2 * 8 + h) * 4096 + row] +
                              lsum_part[(size_t)(3 * 8 + h) * 4096 + row]);

    const unsigned short* Kg = qkvb + 512 + h * 64;
    const unsigned short* Vg = vT + (size_t)h * 64 * 4096;
    float* attnh = attn + (size_t)h * 4096 * 4096;
    unsigned short* PsmW = &Psm[w * 1024];

    const int kr0 = tid >> 3,          kc0 = (tid & 7) << 3;
    const int kr1 = (tid + 256) >> 3;
    const int ld0 = kr0 * 64 + (kc0 ^ ((kr0 & 7) << 3));
    const int ld1 = kr1 * 64 + (kc0 ^ ((kr1 & 7) << 3));

    f32x4 o[4];
    #pragma unroll
    for (int nd = 0; nd < 4; ++nd) o[nd] = (f32x4){0.f, 0.f, 0.f, 0.f};

    {
        bf16x8 ka  = *(const bf16x8*)(Kg + (size_t)(kb + kr0) * 1536 + kc0);
        bf16x8 kbv = *(const bf16x8*)(Kg + (size_t)(kb + kr1) * 1536 + kc0);
        *(bf16x8*)&Ksm[0][ld0] = ka;
        *(bf16x8*)&Ksm[0][ld1] = kbv;
    }
    for (int t = 0; t < 32; ++t) {
        LDS_BARRIER();
        const int cur = t & 1;
        const int k0 = kb + t * 64;
        bf16x8 ka, kbv;
        if (t < 31) {
            const int k0n = k0 + 64;
            ka  = *(const bf16x8*)(Kg + (size_t)(k0n + kr0) * 1536 + kc0);
            kbv = *(const bf16x8*)(Kg + (size_t)(k0n + kr1) * 1536 + kc0);
        }

        #pragma unroll
        for (int nt = 0; nt < 4; ++nt) {
            const int key = nt * 16 + cl;
            f32x4 acc = {0.f, 0.f, 0.f, 0.f};
            #pragma unroll
            for (int ks = 0; ks < 2; ++ks) {
                bf16x8 kf = *(const bf16x8*)&Ksm[cur][key * 64 + ((ks * 32 + rg * 8) ^ ((key & 7) << 3))];
                acc = __builtin_amdgcn_mfma_f32_16x16x32_bf16(kf, qf[ks], acc, 0, 0, 0);
            }
            f32x4 pv;
            #pragma unroll
            for (int r = 0; r < 4; ++r) pv[r] = __expf(acc[r] - M0F) * invl;
            __builtin_nontemporal_store(pv,
                (f32x4*)(attnh + (size_t)(r0 + cl) * 4096 + k0 + nt * 16 + rg * 4));
            u32x2 pw = { pack2(pv[0], pv[1]), pack2(pv[2], pv[3]) };
            *(u32x2*)&PsmW[cl * 64 + ((nt * 16 + rg * 4) ^ ((cl & 7) << 3))] = pw;
        }

        #pragma unroll
        for (int ks = 0; ks < 2; ++ks) {
            bf16x8 pf = *(const bf16x8*)&PsmW[cl * 64 + ((ks * 32 + rg * 8) ^ ((cl & 7) << 3))];
            #pragma unroll
            for (int nd = 0; nd < 4; ++nd) {
                bf16x8 vf = *(const bf16x8*)(Vg + (size_t)(nd * 16 + cl) * 4096 + k0 + ks * 32 + rg * 8);
                o[nd] = __builtin_amdgcn_mfma_f32_16x16x32_bf16(pf, vf, o[nd], 0, 0, 0);
            }
        }

        if (t < 31) {
            *(bf16x8*)&Ksm[cur ^ 1][ld0] = ka;
            *(bf16x8*)&Ksm[cur ^ 1][ld1] = kbv;
        }
    }

    // opart[h][rb][s2][64 rows][64 d]
    float* op = opart + ((((size_t)(h * 64 + rb)) * 2 + s2) * 64) * 64;
    #pragma unroll
    for (int nd = 0; nd < 4; ++nd)
        #pragma unroll
        for (int r = 0; r < 4; ++r)
            op[(size_t)(w * 16 + rg * 4 + r) * 64 + nd * 16 + cl] = o[nd][r];
}

// ---------------- out = (opart summed) @ WoutT + bias (bf16 MFMA, f32 out) ----------------
__global__ __launch_bounds__(256) void outproj_mfma(
    const float* __restrict__ opart,         // [8][64][2][64][64] f32
    const unsigned short* __restrict__ Bt,   // [512][512] bf16 (Wout^T)
    const float* __restrict__ bias,
    float* __restrict__ C)                   // [4096][512] f32
{
    __shared__ unsigned short Asm[64 * 64];
    __shared__ unsigned short Bsm[64 * 64];
    const int n0 = blockIdx.x * 64, m0 = blockIdx.y * 64;
    const int tid = threadIdx.x;
    const int w = tid >> 6, lane = tid & 63;
    const int cl = lane & 15, rg = lane >> 4;
    const int r0s = tid >> 3, c0s = (tid & 7) << 3;
    const int r1s = (tid + 256) >> 3;
    const int l0 = r0s * 64 + (c0s ^ ((r0s & 7) << 3));
    const int l1 = r1s * 64 + (c0s ^ ((r1s & 7) << 3));
    const int rb = m0 >> 6;

    f32x4 acc[4];
    #pragma unroll
    for (int nt = 0; nt < 4; ++nt) acc[nt] = (f32x4){0.f, 0.f, 0.f, 0.f};

    for (int k0 = 0; k0 < 512; k0 += 64) {
        __syncthreads();
        {
            // A[m][k] = opart[h=k>>6][rb][0][r][d] + [1], k = k0 + c0s + j
            const size_t ob = (((size_t)((k0 >> 6) * 64 + rb)) * 2) * 4096;
            const float* p0 = opart + ob + (size_t)r0s * 64 + c0s;
            const float* p1 = opart + ob + (size_t)r1s * 64 + c0s;
            float4 a0 = *(const float4*)p0,        a1 = *(const float4*)(p0 + 4);
            float4 b0 = *(const float4*)(p0+4096), b1 = *(const float4*)(p0 + 4100);
            bf16x8 av; unsigned short* pp = (unsigned short*)&av;
            pp[0] = f2bf(a0.x + b0.x); pp[1] = f2bf(a0.y + b0.y);
            pp[2] = f2bf(a0.z + b0.z); pp[3] = f2bf(a0.w + b0.w);
            pp[4] = f2bf(a1.x + b1.x); pp[5] = f2bf(a1.y + b1.y);
            pp[6] = f2bf(a1.z + b1.z); pp[7] = f2bf(a1.w + b1.w);
            *(bf16x8*)&Asm[l0] = av;
            float4 c0 = *(const float4*)p1,        c1 = *(const float4*)(p1 + 4);
            float4 d0 = *(const float4*)(p1+4096), d1 = *(const float4*)(p1 + 4100);
            bf16x8 aw; unsigned short* qq = (unsigned short*)&aw;
            qq[0] = f2bf(c0.x + d0.x); qq[1] = f2bf(c0.y + d0.y);
            qq[2] = f2bf(c0.z + d0.z); qq[3] = f2bf(c0.w + d0.w);
            qq[4] = f2bf(c1.x + d1.x); qq[5] = f2bf(c1.y + d1.y);
            qq[6] = f2bf(c1.z + d1.z); qq[7] = f2bf(c1.w + d1.w);
            *(bf16x8*)&Asm[l1] = aw;
        }
        *(bf16x8*)&Bsm[l0] = *(const bf16x8*)(Bt + (size_t)(n0 + r0s) * 512 + k0 + c0s);
        *(bf16x8*)&Bsm[l1] = *(const bf16x8*)(Bt + (size_t)(n0 + r1s) * 512 + k0 + c0s);
        __syncthreads();

        bf16x8 af[2];
        af[0] = *(const bf16x8*)&Asm[(w * 16 + cl) * 64 + ((rg * 8) ^ ((cl & 7) << 3))];
        af[1] = *(const bf16x8*)&Asm[(w * 16 + cl) * 64 + ((32 + rg * 8) ^ ((cl & 7) << 3))];
        #pragma unroll
        for (int nt = 0; nt < 4; ++nt) {
            #pragma unroll
            for (int ks = 0; ks < 2; ++ks) {
                bf16x8 bfr = *(const bf16x8*)&Bsm[(nt * 16 + cl) * 64 + ((ks * 32 + rg * 8) ^ ((cl & 7) << 3))];
                acc[nt] = __builtin_amdgcn_mfma_f32_16x16x32_bf16(af[ks], bfr, acc[nt], 0, 0, 0);
            }
        }
    }
    #pragma unroll
    for (int nt = 0; nt < 4; ++nt)
        #pragma unroll
        for (int r = 0; r < 4; ++r)
            C[(size_t)(m0 + w * 16 + rg * 4 + r) * 512 + n0 + nt * 16 + cl] =
                acc[nt][r] + bias[n0 + nt * 16 + cl];
}

extern "C" void kernel_launch(void* const* d_in, const int* in_sizes, int n_in,
                              void* d_out, int out_size, void* d_ws, size_t ws_size,
                              hipStream_t stream)
{
    const float* x    = (const float*)d_in[0];  // [4096, 512]
    const float* Wqkv = (const float*)d_in[1];  // [512, 1536]
    const float* Wout = (const float*)d_in[2];  // [512, 512]
    const float* bout = (const float*)d_in[3];  // [512]

    float* out  = (float*)d_out;                 // [4096, 512]
    float* attn = out + (size_t)4096 * 512;      // [8, 4096, 4096]

    unsigned short* qkvb  = (unsigned short*)d_ws;                 // 12.6 MB
    unsigned short* vT    = qkvb + (size_t)4096 * 1536;            // 4 MB
    unsigned short* Wt    = vT + (size_t)8 * 64 * 4096;            // 1.5 MB
    unsigned short* WtO   = Wt + (size_t)1536 * 512;               // 0.5 MB
    float* lsum_part = (float*)(WtO + (size_t)512 * 512);          // 0.5 MB [4][8][4096]
    float* opart     = lsum_part + (size_t)4 * 8 * 4096;           // 16.8 MB [8][64][2][64][64]

    const dim3 blk(256);

    transpose_w<<<dim3(24, 8), blk, 0, stream>>>(Wqkv, Wt, 1536);
    transpose_w<<<dim3(8, 8), blk, 0, stream>>>(Wout, WtO, 512);
    qkv_mfma<<<dim3(24, 64), blk, 0, stream>>>(x, Wt, qkvb);
    transpose_v<<<dim3(64, 8), blk, 0, stream>>>(qkvb, vT);
    attn_lsum<<<dim3(2048), blk, 0, stream>>>(qkvb, lsum_part);
    attn_pass2<<<dim3(1024), blk, 0, stream>>>(qkvb, vT, lsum_part, attn, opart);
    outproj_mfma<<<dim3(8, 64), blk, 0, stream>>>(opart, WtO, bout, out);
}

// Round 8
// 207.697 us; speedup vs baseline: 1.4615x; 1.4615x over previous
//
#include <hip/hip_runtime.h>

typedef __attribute__((ext_vector_type(8))) short bf16x8;
typedef __attribute__((ext_vector_type(4))) float f32x4;
typedef __attribute__((ext_vector_type(2))) unsigned u32x2;

#define M0F 14.0f

__device__ inline float bf2f(unsigned short b) {
    unsigned u = ((unsigned)b) << 16;
    float f; __builtin_memcpy(&f, &u, 4); return f;
}
__device__ inline unsigned short f2bf(float f) {
    unsigned u; __builtin_memcpy(&u, &f, 4);
    u = (u + 0x7fff + ((u >> 16) & 1)) >> 16;
    return (unsigned short)u;
}
__device__ inline unsigned pack2(float a, float b) {
    return (unsigned)f2bf(a) | ((unsigned)f2bf(b) << 16);
}

// LDS-visibility barrier; leaves global stores in flight
#define LDS_BARRIER() do { \
    asm volatile("s_waitcnt lgkmcnt(0)" ::: "memory"); \
    __builtin_amdgcn_s_barrier(); \
} while (0)

// ---------------- W [K][N] f32 -> Wt [N][K=512] bf16 ----------------
__global__ __launch_bounds__(256) void transpose_w(
    const float* __restrict__ W, unsigned short* __restrict__ Wt, int ldn)
{
    __shared__ unsigned short t[64][72];
    const int n0 = blockIdx.x * 64, k0 = blockIdx.y * 64;
    const int tid = threadIdx.x;
    for (int i = tid; i < 1024; i += 256) {
        int r = i >> 4, c4 = (i & 15) << 2;
        float4 v = *(const float4*)(W + (size_t)(k0 + r) * ldn + n0 + c4);
        t[c4 + 0][r] = f2bf(v.x); t[c4 + 1][r] = f2bf(v.y);
        t[c4 + 2][r] = f2bf(v.z); t[c4 + 3][r] = f2bf(v.w);
    }
    __syncthreads();
    for (int i = tid; i < 512; i += 256) {
        int n = i >> 3, k4 = (i & 7) << 3;
        bf16x8 v = *(const bf16x8*)&t[n][k4];
        *(bf16x8*)(Wt + (size_t)(n0 + n) * 512 + k0 + k4) = v;
    }
}

// ---------------- qkv = x @ Wqkv via bf16 MFMA ----------------
__global__ __launch_bounds__(256) void qkv_mfma(
    const float* __restrict__ x, const unsigned short* __restrict__ Wt,
    unsigned short* __restrict__ qkvb)
{
    __shared__ unsigned short Asm[64 * 64];
    __shared__ unsigned short Bsm[64 * 64];
    const int n0 = blockIdx.x * 64, m0 = blockIdx.y * 64;
    const int tid = threadIdx.x;
    const int w = tid >> 6, lane = tid & 63;
    const int cl = lane & 15, rg = lane >> 4;
    const int r0s = tid >> 3, c0s = (tid & 7) << 3;
    const int r1s = (tid + 256) >> 3;
    const int l0 = r0s * 64 + (c0s ^ ((r0s & 7) << 3));
    const int l1 = r1s * 64 + (c0s ^ ((r1s & 7) << 3));

    f32x4 acc[4];
    #pragma unroll
    for (int nt = 0; nt < 4; ++nt) acc[nt] = (f32x4){0.f, 0.f, 0.f, 0.f};

    for (int k0 = 0; k0 < 512; k0 += 64) {
        __syncthreads();
        {
            const float* ap = x + (size_t)(m0 + r0s) * 512 + k0 + c0s;
            float4 f0 = *(const float4*)ap, f1 = *(const float4*)(ap + 4);
            bf16x8 av; unsigned short* pp = (unsigned short*)&av;
            pp[0] = f2bf(f0.x); pp[1] = f2bf(f0.y); pp[2] = f2bf(f0.z); pp[3] = f2bf(f0.w);
            pp[4] = f2bf(f1.x); pp[5] = f2bf(f1.y); pp[6] = f2bf(f1.z); pp[7] = f2bf(f1.w);
            *(bf16x8*)&Asm[l0] = av;
            const float* aq = x + (size_t)(m0 + r1s) * 512 + k0 + c0s;
            float4 g0 = *(const float4*)aq, g1 = *(const float4*)(aq + 4);
            bf16x8 aw; unsigned short* qq = (unsigned short*)&aw;
            qq[0] = f2bf(g0.x); qq[1] = f2bf(g0.y); qq[2] = f2bf(g0.z); qq[3] = f2bf(g0.w);
            qq[4] = f2bf(g1.x); qq[5] = f2bf(g1.y); qq[6] = f2bf(g1.z); qq[7] = f2bf(g1.w);
            *(bf16x8*)&Asm[l1] = aw;
        }
        *(bf16x8*)&Bsm[l0] = *(const bf16x8*)(Wt + (size_t)(n0 + r0s) * 512 + k0 + c0s);
        *(bf16x8*)&Bsm[l1] = *(const bf16x8*)(Wt + (size_t)(n0 + r1s) * 512 + k0 + c0s);
        __syncthreads();

        bf16x8 af[2];
        af[0] = *(const bf16x8*)&Asm[(w * 16 + cl) * 64 + ((rg * 8) ^ ((cl & 7) << 3))];
        af[1] = *(const bf16x8*)&Asm[(w * 16 + cl) * 64 + ((32 + rg * 8) ^ ((cl & 7) << 3))];
        #pragma unroll
        for (int nt = 0; nt < 4; ++nt) {
            #pragma unroll
            for (int ks = 0; ks < 2; ++ks) {
                bf16x8 bfr = *(const bf16x8*)&Bsm[(nt * 16 + cl) * 64 + ((ks * 32 + rg * 8) ^ ((cl & 7) << 3))];
                acc[nt] = __builtin_amdgcn_mfma_f32_16x16x32_bf16(af[ks], bfr, acc[nt], 0, 0, 0);
            }
        }
    }
    #pragma unroll
    for (int nt = 0; nt < 4; ++nt)
        #pragma unroll
        for (int r = 0; r < 4; ++r)
            qkvb[(size_t)(m0 + w * 16 + rg * 4 + r) * 1536 + n0 + nt * 16 + cl] = f2bf(acc[nt][r]);
}

// ---------------- V transpose: qkv V columns -> vT[h][d][key] ----------------
__global__ __launch_bounds__(256) void transpose_v(
    const unsigned short* __restrict__ qkvb, unsigned short* __restrict__ vT)
{
    __shared__ unsigned short tile[64][72];
    const int h = blockIdx.y, k0 = blockIdx.x * 64;
    const int tid = threadIdx.x;

    for (int c = tid; c < 512; c += 256) {
        int key = c >> 3, d0 = (c & 7) << 3;
        bf16x8 v = *(const bf16x8*)(qkvb + (size_t)(k0 + key) * 1536 + 1024 + h * 64 + d0);
        #pragma unroll
        for (int j = 0; j < 8; ++j) tile[d0 + j][key] = ((const unsigned short*)&v)[j];
    }
    __syncthreads();
    for (int c = tid; c < 512; c += 256) {
        int d = c >> 3, kk0 = (c & 7) << 3;
        bf16x8 v = *(const bf16x8*)&tile[d][kk0];
        *(bf16x8*)(vT + ((size_t)h * 64 + d) * 4096 + k0 + kk0) = v;
    }
}

// ---------------- pass 1: partial row sums, K-split x4, LDS-staged ----------------
// grid 2048: h = bid&7 (XCD pin), s = (bid>>3)&3 (key quarter), rb = bid>>5 (64 rows)
__global__ __launch_bounds__(256) void attn_lsum(
    const unsigned short* __restrict__ qkvb, float* __restrict__ lsum_part)
{
    __shared__ unsigned short Ksm[2][64 * 64];
    const int bid = blockIdx.x;
    const int h = bid & 7, s = (bid >> 3) & 3, rb = bid >> 5;
    const int tid = threadIdx.x;
    const int w = tid >> 6, lane = tid & 63;
    const int cl = lane & 15, rg = lane >> 4;
    const int r0 = rb * 64 + w * 16;
    const int kb = s * 1024;

    bf16x8 qf[2];
    #pragma unroll
    for (int ks = 0; ks < 2; ++ks) {
        qf[ks] = *(const bf16x8*)(qkvb + (size_t)(r0 + cl) * 1536 + h * 64 + ks * 32 + rg * 8);
        unsigned short* qp = (unsigned short*)&qf[ks];
        #pragma unroll
        for (int j = 0; j < 8; ++j) qp[j] = f2bf(bf2f(qp[j]) * 0.125f);
    }

    const unsigned short* Kg = qkvb + 512 + h * 64;

    const int kr0 = tid >> 3,          kc0 = (tid & 7) << 3;
    const int kr1 = (tid + 256) >> 3;
    const int ld0 = kr0 * 64 + (kc0 ^ ((kr0 & 7) << 3));
    const int ld1 = kr1 * 64 + (kc0 ^ ((kr1 & 7) << 3));

    {
        bf16x8 ka = *(const bf16x8*)(Kg + (size_t)(kb + kr0) * 1536 + kc0);
        bf16x8 kbv = *(const bf16x8*)(Kg + (size_t)(kb + kr1) * 1536 + kc0);
        *(bf16x8*)&Ksm[0][ld0] = ka;
        *(bf16x8*)&Ksm[0][ld1] = kbv;
    }
    float lsum = 0.f;
    for (int t = 0; t < 16; ++t) {
        LDS_BARRIER();
        const int cur = t & 1;
        bf16x8 ka, kbv;
        if (t < 15) {
            const int k0n = kb + (t + 1) * 64;
            ka  = *(const bf16x8*)(Kg + (size_t)(k0n + kr0) * 1536 + kc0);
            kbv = *(const bf16x8*)(Kg + (size_t)(k0n + kr1) * 1536 + kc0);
        }
        #pragma unroll
        for (int nt = 0; nt < 4; ++nt) {
            const int key = nt * 16 + cl;
            f32x4 acc = {0.f, 0.f, 0.f, 0.f};
            #pragma unroll
            for (int ks = 0; ks < 2; ++ks) {
                bf16x8 kf = *(const bf16x8*)&Ksm[cur][key * 64 + ((ks * 32 + rg * 8) ^ ((key & 7) << 3))];
                acc = __builtin_amdgcn_mfma_f32_16x16x32_bf16(kf, qf[ks], acc, 0, 0, 0);
            }
            #pragma unroll
            for (int r = 0; r < 4; ++r) lsum += __expf(acc[r] - M0F);
        }
        if (t < 15) {
            *(bf16x8*)&Ksm[cur ^ 1][ld0] = ka;
            *(bf16x8*)&Ksm[cur ^ 1][ld1] = kbv;
        }
    }
    lsum += __shfl_xor(lsum, 16);
    lsum += __shfl_xor(lsum, 32);
    if (rg == 0)
        lsum_part[((size_t)(s * 8 + h) << 12) + r0 + cl] = lsum;
}

// ---------------- pass 2: P write + partial PV, K-split x2, LDS-staged ----------------
// grid 1024: h = bid&7, s2 = (bid>>3)&1, rb = bid>>4 (64 rows); 4 blocks/CU (40KB LDS)
// attn store goes through Psm: 256B-contiguous segments instead of 64B.
__global__ __launch_bounds__(256) void attn_pass2(
    const unsigned short* __restrict__ qkvb,
    const unsigned short* __restrict__ vT,
    const float* __restrict__ lsum_part,
    float* __restrict__ attn,
    float* __restrict__ opart)
{
    __shared__ unsigned short Ksm[2][64 * 64];
    __shared__ unsigned short Vsm[2][64 * 64];
    __shared__ unsigned short Psm[4 * 16 * 64];

    const int bid = blockIdx.x;
    const int h = bid & 7, s2 = (bid >> 3) & 1, rb = bid >> 4;
    const int tid = threadIdx.x;
    const int w = tid >> 6, lane = tid & 63;
    const int cl = lane & 15, rg = lane >> 4;
    const int r0 = rb * 64 + w * 16;
    const int kb = s2 * 2048;

    bf16x8 qf[2];
    #pragma unroll
    for (int ks = 0; ks < 2; ++ks) {
        qf[ks] = *(const bf16x8*)(qkvb + (size_t)(r0 + cl) * 1536 + h * 64 + ks * 32 + rg * 8);
        unsigned short* qp = (unsigned short*)&qf[ks];
        #pragma unroll
        for (int j = 0; j < 8; ++j) qp[j] = f2bf(bf2f(qp[j]) * 0.125f);
    }

    const int row = r0 + cl;
    const float invl = 1.f / (lsum_part[(size_t)(0 * 8 + h) * 4096 + row] +
                              lsum_part[(size_t)(1 * 8 + h) * 4096 + row] +
                              lsum_part[(size_t)(2 * 8 + h) * 4096 + row] +
                              lsum_part[(size_t)(3 * 8 + h) * 4096 + row]);

    const unsigned short* Kg = qkvb + 512 + h * 64;
    const unsigned short* Vg = vT + (size_t)h * 64 * 4096;
    float* attnh = attn + (size_t)h * 4096 * 4096;
    unsigned short* PsmW = &Psm[w * 1024];

    const int kr0 = tid >> 3,          kc0 = (tid & 7) << 3;
    const int kr1 = (tid + 256) >> 3;
    const int ld0 = kr0 * 64 + (kc0 ^ ((kr0 & 7) << 3));
    const int ld1 = kr1 * 64 + (kc0 ^ ((kr1 & 7) << 3));

    // store-phase mapping: lane -> (row rr, col cc) with 256B-contiguous segments
    const int srow = lane >> 4;          // + 4*b
    const int scol = (lane & 15) * 4;

    f32x4 o[4];
    #pragma unroll
    for (int nd = 0; nd < 4; ++nd) o[nd] = (f32x4){0.f, 0.f, 0.f, 0.f};

    {
        bf16x8 ka  = *(const bf16x8*)(Kg + (size_t)(kb + kr0) * 1536 + kc0);
        bf16x8 kbv = *(const bf16x8*)(Kg + (size_t)(kb + kr1) * 1536 + kc0);
        bf16x8 va  = *(const bf16x8*)(Vg + (size_t)kr0 * 4096 + kb + kc0);
        bf16x8 vb  = *(const bf16x8*)(Vg + (size_t)kr1 * 4096 + kb + kc0);
        *(bf16x8*)&Ksm[0][ld0] = ka;
        *(bf16x8*)&Ksm[0][ld1] = kbv;
        *(bf16x8*)&Vsm[0][ld0] = va;
        *(bf16x8*)&Vsm[0][ld1] = vb;
    }
    for (int t = 0; t < 32; ++t) {
        LDS_BARRIER();
        const int cur = t & 1;
        const int k0 = kb + t * 64;
        bf16x8 ka, kbv, va, vb;
        if (t < 31) {
            const int k0n = k0 + 64;
            ka  = *(const bf16x8*)(Kg + (size_t)(k0n + kr0) * 1536 + kc0);
            kbv = *(const bf16x8*)(Kg + (size_t)(k0n + kr1) * 1536 + kc0);
            va  = *(const bf16x8*)(Vg + (size_t)kr0 * 4096 + k0n + kc0);
            vb  = *(const bf16x8*)(Vg + (size_t)kr1 * 4096 + k0n + kc0);
        }

        // QK^T -> P (bf16) into Psm only
        #pragma unroll
        for (int nt = 0; nt < 4; ++nt) {
            const int key = nt * 16 + cl;
            f32x4 acc = {0.f, 0.f, 0.f, 0.f};
            #pragma unroll
            for (int ks = 0; ks < 2; ++ks) {
                bf16x8 kf = *(const bf16x8*)&Ksm[cur][key * 64 + ((ks * 32 + rg * 8) ^ ((key & 7) << 3))];
                acc = __builtin_amdgcn_mfma_f32_16x16x32_bf16(kf, qf[ks], acc, 0, 0, 0);
            }
            f32x4 pv;
            #pragma unroll
            for (int r = 0; r < 4; ++r) pv[r] = __expf(acc[r] - M0F) * invl;
            u32x2 pw = { pack2(pv[0], pv[1]), pack2(pv[2], pv[3]) };
            *(u32x2*)&PsmW[cl * 64 + ((nt * 16 + rg * 4) ^ ((cl & 7) << 3))] = pw;
        }

        // attn store: read back Psm with contiguous mapping (4 rows x 256B per instr)
        #pragma unroll
        for (int b = 0; b < 4; ++b) {
            const int rr = b * 4 + srow;
            u32x2 pr = *(const u32x2*)&PsmW[rr * 64 + (scol ^ ((rr & 7) << 3))];
            f32x4 pf4;
            pf4[0] = bf2f((unsigned short)(pr[0] & 0xffffu));
            pf4[1] = bf2f((unsigned short)(pr[0] >> 16));
            pf4[2] = bf2f((unsigned short)(pr[1] & 0xffffu));
            pf4[3] = bf2f((unsigned short)(pr[1] >> 16));
            __builtin_nontemporal_store(pf4,
                (f32x4*)(attnh + (size_t)(r0 + rr) * 4096 + k0 + scol));
        }

        // PV: A = P, B = V^T
        #pragma unroll
        for (int ks = 0; ks < 2; ++ks) {
            bf16x8 pf = *(const bf16x8*)&PsmW[cl * 64 + ((ks * 32 + rg * 8) ^ ((cl & 7) << 3))];
            #pragma unroll
            for (int nd = 0; nd < 4; ++nd) {
                const int d = nd * 16 + cl;
                bf16x8 vf = *(const bf16x8*)&Vsm[cur][d * 64 + ((ks * 32 + rg * 8) ^ ((d & 7) << 3))];
                o[nd] = __builtin_amdgcn_mfma_f32_16x16x32_bf16(pf, vf, o[nd], 0, 0, 0);
            }
        }

        if (t < 31) {
            *(bf16x8*)&Ksm[cur ^ 1][ld0] = ka;
            *(bf16x8*)&Ksm[cur ^ 1][ld1] = kbv;
            *(bf16x8*)&Vsm[cur ^ 1][ld0] = va;
            *(bf16x8*)&Vsm[cur ^ 1][ld1] = vb;
        }
    }

    // opart[h][rb][s2][64 rows][64 d]
    float* op = opart + ((((size_t)(h * 64 + rb)) * 2 + s2) * 64) * 64;
    #pragma unroll
    for (int nd = 0; nd < 4; ++nd)
        #pragma unroll
        for (int r = 0; r < 4; ++r)
            op[(size_t)(w * 16 + rg * 4 + r) * 64 + nd * 16 + cl] = o[nd][r];
}

// ---------------- reduce_o: sum 2 key-half partials -> outhb bf16 ----------------
__global__ __launch_bounds__(256) void reduce_o(
    const float* __restrict__ opart, unsigned short* __restrict__ outhb)
{
    const int i = (blockIdx.x * 256 + threadIdx.x) * 4;   // over [4096][512]
    const int row = i >> 9, c = i & 511;
    const int h = c >> 6, d = c & 63;
    const int rb = row >> 6, r = row & 63;
    const size_t base = (((size_t)(h * 64 + rb) * 2) * 64 + r) * 64 + d;
    float4 a = *(const float4*)(opart + base);
    float4 b = *(const float4*)(opart + base + 4096);  // s2=1
    u32x2 pw = { pack2(a.x + b.x, a.y + b.y), pack2(a.z + b.z, a.w + b.w) };
    *(u32x2*)(outhb + i) = pw;
}

// ---------------- out = outhb @ WoutT + bias (bf16 MFMA, f32 out) ----------------
__global__ __launch_bounds__(256) void outproj_mfma(
    const unsigned short* __restrict__ A,
    const unsigned short* __restrict__ Bt,
    const float* __restrict__ bias,
    float* __restrict__ C)
{
    __shared__ unsigned short Asm[64 * 64];
    __shared__ unsigned short Bsm[64 * 64];
    const int n0 = blockIdx.x * 64, m0 = blockIdx.y * 64;
    const int tid = threadIdx.x;
    const int w = tid >> 6, lane = tid & 63;
    const int cl = lane & 15, rg = lane >> 4;
    const int r0s = tid >> 3, c0s = (tid & 7) << 3;
    const int r1s = (tid + 256) >> 3;
    const int l0 = r0s * 64 + (c0s ^ ((r0s & 7) << 3));
    const int l1 = r1s * 64 + (c0s ^ ((r1s & 7) << 3));

    f32x4 acc[4];
    #pragma unroll
    for (int nt = 0; nt < 4; ++nt) acc[nt] = (f32x4){0.f, 0.f, 0.f, 0.f};

    for (int k0 = 0; k0 < 512; k0 += 64) {
        __syncthreads();
        *(bf16x8*)&Asm[l0] = *(const bf16x8*)(A + (size_t)(m0 + r0s) * 512 + k0 + c0s);
        *(bf16x8*)&Asm[l1] = *(const bf16x8*)(A + (size_t)(m0 + r1s) * 512 + k0 + c0s);
        *(bf16x8*)&Bsm[l0] = *(const bf16x8*)(Bt + (size_t)(n0 + r0s) * 512 + k0 + c0s);
        *(bf16x8*)&Bsm[l1] = *(const bf16x8*)(Bt + (size_t)(n0 + r1s) * 512 + k0 + c0s);
        __syncthreads();

        bf16x8 af[2];
        af[0] = *(const bf16x8*)&Asm[(w * 16 + cl) * 64 + ((rg * 8) ^ ((cl & 7) << 3))];
        af[1] = *(const bf16x8*)&Asm[(w * 16 + cl) * 64 + ((32 + rg * 8) ^ ((cl & 7) << 3))];
        #pragma unroll
        for (int nt = 0; nt < 4; ++nt) {
            #pragma unroll
            for (int ks = 0; ks < 2; ++ks) {
                bf16x8 bfr = *(const bf16x8*)&Bsm[(nt * 16 + cl) * 64 + ((ks * 32 + rg * 8) ^ ((cl & 7) << 3))];
                acc[nt] = __builtin_amdgcn_mfma_f32_16x16x32_bf16(af[ks], bfr, acc[nt], 0, 0, 0);
            }
        }
    }
    #pragma unroll
    for (int nt = 0; nt < 4; ++nt)
        #pragma unroll
        for (int r = 0; r < 4; ++r)
            C[(size_t)(m0 + w * 16 + rg * 4 + r) * 512 + n0 + nt * 16 + cl] =
                acc[nt][r] + bias[n0 + nt * 16 + cl];
}

extern "C" void kernel_launch(void* const* d_in, const int* in_sizes, int n_in,
                              void* d_out, int out_size, void* d_ws, size_t ws_size,
                              hipStream_t stream)
{
    const float* x    = (const float*)d_in[0];  // [4096, 512]
    const float* Wqkv = (const float*)d_in[1];  // [512, 1536]
    const float* Wout = (const float*)d_in[2];  // [512, 512]
    const float* bout = (const float*)d_in[3];  // [512]

    float* out  = (float*)d_out;                 // [4096, 512]
    float* attn = out + (size_t)4096 * 512;      // [8, 4096, 4096]

    unsigned short* qkvb  = (unsigned short*)d_ws;                 // 12.6 MB
    unsigned short* vT    = qkvb + (size_t)4096 * 1536;            // 4 MB
    unsigned short* Wt    = vT + (size_t)8 * 64 * 4096;            // 1.5 MB
    unsigned short* WtO   = Wt + (size_t)1536 * 512;               // 0.5 MB
    unsigned short* outhb = WtO + (size_t)512 * 512;               // 4 MB
    float* lsum_part = (float*)(outhb + (size_t)4096 * 512);       // 0.5 MB [4][8][4096]
    float* opart     = lsum_part + (size_t)4 * 8 * 4096;           // 16.8 MB [8][64][2][64][64]

    const dim3 blk(256);

    transpose_w<<<dim3(24, 8), blk, 0, stream>>>(Wqkv, Wt, 1536);
    transpose_w<<<dim3(8, 8), blk, 0, stream>>>(Wout, WtO, 512);
    qkv_mfma<<<dim3(24, 64), blk, 0, stream>>>(x, Wt, qkvb);
    transpose_v<<<dim3(64, 8), blk, 0, stream>>>(qkvb, vT);
    attn_lsum<<<dim3(2048), blk, 0, stream>>>(qkvb, lsum_part);
    attn_pass2<<<dim3(1024), blk, 0, stream>>>(qkvb, vT, lsum_part, attn, opart);
    reduce_o<<<dim3(2048), blk, 0, stream>>>(opart, outhb);
    outproj_mfma<<<dim3(8, 64), blk, 0, stream>>>(outhb, WtO, bout, out);
}